// Round 5
// baseline (1091.175 us; speedup 1.0000x reference)
//
#include <hip/hip_runtime.h>
#include <math.h>

#define NMS_THRESH 0.7f
#define NANCH 36864
#define TOPK 6000
#define NWORDS 94    // ceil(6000/64)
#define POSTK 300
#define MAXCAND 10240

// ---------------- conv 3x3 + bias + relu, batch 0 only ----------------
// grid 512 = y_tile(16) x co_tile(32); block 256 (4 waves)
// block: 16 co x (4 rows x 64 cols). wave w owns co [co0+4w, +4) (uniform).
// thread: 4px x 4co. Weights: float3 loads from W, 3-slot rotating prefetch
// (distance 2 groups); slot index == ky (G mod 3), all compile-time.
// LDS: double-buffered halo-free tile [16ci][6rows][68] (stride 68 breaks
// row bank aliasing); cols 64..67 pre-zeroed; x-edges fixed in registers.
__global__ __launch_bounds__(256, 2)
void k_conv(const float* __restrict__ feat, const float* __restrict__ W,
            const float* __restrict__ bias, float* __restrict__ tout)
{
    __shared__ float sS[2 * 6528];   // 52,224 B

    const int blk = blockIdx.x;
    const int ct  = blk & 31;             // co-tile 0..31
    const int yt  = blk >> 5;             // y-tile 0..15
    const int cob = ct << 4;
    const int y0  = yt << 2;
    const int tid = threadIdx.x;
    const int lane = tid & 63;
    const int wid = __builtin_amdgcn_readfirstlane(tid >> 6);
    const int co0 = cob + (wid << 2);
    const int ly = lane >> 4;             // row 0..3
    const int lx = (lane & 15) << 2;      // col 0..60 step 4

    // staging geometry: 16ci x 6rows x 17 float4-segments = 1632 units
    // (seg 16 = pad cols 64..67, zero-filled). 6/thread + 7th for tid<96.
    int g_ofs[7]; int l_ofs[7]; bool g_ok[7]; bool w_do[7];
    #pragma unroll
    for (int q = 0; q < 7; ++q) {
        int u = q * 256 + tid;            // valid < 1632
        int ci = u / 102; int rem = u - ci * 102;
        int rr = rem / 17; int seg = rem - rr * 17;
        int gy = y0 - 1 + rr;
        w_do[q] = (u < 1632);
        g_ok[q] = w_do[q] && (seg < 16) && (gy >= 0) && (gy < 64);
        g_ofs[q] = ((ci & 15) << 12) + ((gy & 63) << 6) + ((seg & 15) << 2);
        l_ofs[q] = ci * 408 + rr * 68 + (seg << 2);
    }

    const float* wco = W + (size_t)co0 * 4608;   // + j*4608 + ci*9 + ky*3

    float3 wq[3][4];                      // slot = ky of the group it holds
#define WLOAD(slot, ci2, ky2) do {                                        \
        _Pragma("unroll")                                                 \
        for (int _j = 0; _j < 4; ++_j)                                    \
            wq[slot][_j] = *(const float3*)(wco + (size_t)_j * 4608       \
                                            + (ci2) * 9 + (ky2) * 3);    \
    } while (0)

    float acc[4][4];
    #pragma unroll
    for (int i = 0; i < 4; ++i)
        #pragma unroll
        for (int j = 0; j < 4; ++j) acc[i][j] = 0.f;

    // prologue: stage cc=0 into buffer 0; preload weight groups G=0,1
    {
        float4 r0[7];
        #pragma unroll
        for (int q = 0; q < 7; ++q)
            r0[q] = g_ok[q] ? *(const float4*)(feat + g_ofs[q])
                            : make_float4(0.f, 0.f, 0.f, 0.f);
        #pragma unroll
        for (int q = 0; q < 7; ++q)
            if (w_do[q]) *(float4*)&sS[l_ofs[q]] = r0[q];
    }
    WLOAD(0, 0, 0);
    WLOAD(1, 0, 1);
    __syncthreads();

    int p = 0;
    for (int cc = 0; cc < 32; ++cc) {
        const int pbase = p * 6528;
        const int cib = cc << 4;
        const bool more = cc < 31;
        float4 r[7];
        #pragma unroll
        for (int ci = 0; ci < 16; ++ci) {
            if (ci == 8) {
                if (more) {
                    const float* fsrc = feat + ((size_t)(cc + 1) << 16);
                    #pragma unroll
                    for (int q = 0; q < 7; ++q)
                        r[q] = g_ok[q] ? *(const float4*)(fsrc + g_ofs[q])
                                       : make_float4(0.f, 0.f, 0.f, 0.f);
                }
            }
            #pragma unroll
            for (int ky = 0; ky < 3; ++ky) {
                const int g = ci * 3 + ky;           // 0..47, compile-time
                {   // prefetch group G+2 into slot (g+2)%3 (== its ky)
                    int ci2 = cib + ((g + 2) / 3);   // runtime uniform
                    if (ci2 > 511) ci2 = 511;
                    const int ky2 = (g + 2) % 3;     // compile-time
                    WLOAD(ky2, ci2, ky2);
                }
                // feat fragment (identical numerics to validated round-4)
                const float* rb = sS + pbase + ci * 408 + (ly + ky) * 68;
                float4 f4 = *(const float4*)&rb[lx];
                int c0 = lx ? lx - 1 : 0;
                int c5 = (lx < 60) ? lx + 4 : 63;
                float t0 = rb[c0];
                float t5 = rb[c5];
                float fr[6];
                fr[0] = lx ? t0 : 0.f;
                fr[1] = f4.x; fr[2] = f4.y; fr[3] = f4.z; fr[4] = f4.w;
                fr[5] = (lx < 60) ? t5 : 0.f;
                #pragma unroll
                for (int kx = 0; kx < 3; ++kx)
                    #pragma unroll
                    for (int i = 0; i < 4; ++i)
                        #pragma unroll
                        for (int j = 0; j < 4; ++j) {
                            float wv = (kx == 0) ? wq[ky][j].x
                                     : (kx == 1) ? wq[ky][j].y
                                                 : wq[ky][j].z;
                            acc[i][j] = fmaf(fr[i + kx], wv, acc[i][j]);
                        }
            }
        }
        if (more) {
            const int wb = (p ^ 1) * 6528;
            #pragma unroll
            for (int q = 0; q < 7; ++q)
                if (w_do[q]) *(float4*)&sS[wb + l_ofs[q]] = r[q];
        }
        __syncthreads();
        p ^= 1;
    }
#undef WLOAD

    const int y = y0 + ly;
    #pragma unroll
    for (int j = 0; j < 4; ++j) {
        const float bv = bias[co0 + j];
        float4 o;
        o.x = fmaxf(acc[0][j] + bv, 0.f);
        o.y = fmaxf(acc[1][j] + bv, 0.f);
        o.z = fmaxf(acc[2][j] + bv, 0.f);
        o.w = fmaxf(acc[3][j] + bv, 0.f);
        *(float4*)&tout[((size_t)(co0 + j) << 12) + (y << 6) + lx] = o;
    }
}

// ---------------- 1x1 heads: wave = 64 px of one channel ----------------
__global__ __launch_bounds__(64)
void k_heads(const float* __restrict__ t, const float* __restrict__ cls_w,
             const float* __restrict__ cls_b, const float* __restrict__ reg_w,
             const float* __restrict__ reg_b, float* __restrict__ heads)
{
    const int bid = blockIdx.x;
    const int ch = bid % 45;                  // uniform
    const int pt = bid / 45;
    const int px = (pt << 6) + threadIdx.x;
    const float* wp; float bv;
    if (ch < 9) { wp = cls_w + ch * 512;       bv = cls_b[ch]; }
    else        { wp = reg_w + (ch - 9) * 512; bv = reg_b[ch - 9]; }
    float acc = bv;
    #pragma unroll 8
    for (int ci = 0; ci < 512; ++ci)
        acc = fmaf(t[((size_t)ci << 12) + px], wp[ci], acc);
    heads[((size_t)ch << 12) + px] = acc;
}

// ---------------- decode + sigmoid + clip + validity + hist1 (fused) ----------------
__global__ void k_decode(const float* __restrict__ heads,
                         float* __restrict__ score, float* __restrict__ validf,
                         float* __restrict__ box, unsigned* __restrict__ hist)
{
    __shared__ unsigned lh[4096];
    const int tid = threadIdx.x;
    for (int q = tid; q < 4096; q += 256) lh[q] = 0u;
    __syncthreads();

    int idx = blockIdx.x * 256 + tid;
    int p = idx / 9, a = idx - p * 9;
    int yq = p >> 6, xq = p & 63;
    const double scl[3] = {128.0, 256.0, 512.0};
    const double rat[3] = {0.5, 1.0, 2.0};
    double s = scl[a / 3], r = rat[a % 3];
    float bw = (float)(s * sqrt(1.0 / r) * 0.5);
    float bh = (float)(s * sqrt(r) * 0.5);
    float sx = xq * 16.0f + 8.0f;
    float sy = yq * 16.0f + 8.0f;
    float a0 = sx - bw, a1 = sy - bh, a2 = sx + bw, a3 = sy + bh;
    float wa = a2 - a0, ha = a3 - a1;
    float cx = a0 + 0.5f * wa, cy = a1 + 0.5f * ha;
    float logit = heads[(size_t)a * 4096 + p];
    float dx = heads[(size_t)(9  + 4 * a) * 4096 + p];
    float dy = heads[(size_t)(10 + 4 * a) * 4096 + p];
    float dw = fminf(heads[(size_t)(11 + 4 * a) * 4096 + p], 4.135166556742356f);
    float dh = fminf(heads[(size_t)(12 + 4 * a) * 4096 + p], 4.135166556742356f);
    float pcx = dx * wa + cx, pcy = dy * ha + cy;
    float pw = expf(dw) * wa, ph = expf(dh) * ha;
    float x1 = pcx - 0.5f * pw, y1 = pcy - 0.5f * ph;
    float x2 = pcx + 0.5f * pw, y2 = pcy + 0.5f * ph;
    x1 = fminf(fmaxf(x1, 0.f), 1024.f); y1 = fminf(fmaxf(y1, 0.f), 1024.f);
    x2 = fminf(fmaxf(x2, 0.f), 1024.f); y2 = fminf(fmaxf(y2, 0.f), 1024.f);
    float wv = x2 - x1, hv = y2 - y1;
    float sc = 1.f / (1.f + expf(-logit));
    score[idx]  = sc;
    validf[idx] = (wv >= 1.f && hv >= 1.f) ? 1.f : 0.f;
    box[idx * 4 + 0] = x1; box[idx * 4 + 1] = y1;
    box[idx * 4 + 2] = x2; box[idx * 4 + 3] = y2;

    atomicAdd(&lh[__float_as_uint(sc) >> 19], 1u);
    __syncthreads();
    for (int q = tid; q < 4096; q += 256) if (lh[q]) atomicAdd(&hist[q], lh[q]);
}

// ---------------- top-k cutoff machinery ----------------
__global__ void k_zero(unsigned* __restrict__ p) {
    int i = blockIdx.x * 256 + threadIdx.x;
    if (i < 8448) p[i] = 0u;   // hist(4096) + hist2(4096) + meta
}

__global__ void k_cut1(const unsigned* __restrict__ hist, unsigned* __restrict__ meta) {
    __shared__ unsigned hh[4096];
    __shared__ unsigned gs[256];
    int tid = threadIdx.x;
    for (int q = tid; q < 4096; q += 256) hh[q] = hist[q];
    __syncthreads();
    unsigned s = 0;
    #pragma unroll
    for (int k = 0; k < 16; ++k) s += hh[tid * 16 + k];
    gs[tid] = s;
    __syncthreads();
    if (tid == 0) {
        unsigned cum = 0;
        for (int g = 255; g >= 0; --g) {
            if (cum + gs[g] >= (unsigned)TOPK) {
                for (int b = g * 16 + 15; b >= g * 16; --b) {
                    if (cum + hh[b] >= (unsigned)TOPK) { meta[2] = (unsigned)b; meta[3] = cum; break; }
                    cum += hh[b];
                }
                break;
            }
            cum += gs[g];
        }
    }
}

__global__ void k_hist2(const float* __restrict__ score, const unsigned* __restrict__ meta,
                        unsigned* __restrict__ hist2) {
    int idx = blockIdx.x * 256 + threadIdx.x;
    unsigned bits = __float_as_uint(score[idx]);
    if ((bits >> 19) == meta[2]) atomicAdd(&hist2[(bits >> 7) & 0xFFFu], 1u);
}

__global__ void k_cut2(const unsigned* __restrict__ hist2, unsigned* __restrict__ meta) {
    __shared__ unsigned hh[4096];
    __shared__ unsigned gs[256];
    int tid = threadIdx.x;
    for (int q = tid; q < 4096; q += 256) hh[q] = hist2[q];
    __syncthreads();
    unsigned s = 0;
    #pragma unroll
    for (int k = 0; k < 16; ++k) s += hh[tid * 16 + k];
    gs[tid] = s;
    __syncthreads();
    if (tid == 0) {
        unsigned cum = meta[3];
        unsigned B = meta[2];
        unsigned cut = B << 19;
        for (int g = 255; g >= 0; --g) {
            if (cum + gs[g] >= (unsigned)TOPK) {
                for (int b = g * 16 + 15; b >= g * 16; --b) {
                    cum += hh[b];
                    if (cum >= (unsigned)TOPK) { cut = (B << 19) | ((unsigned)b << 7); break; }
                }
                break;
            }
            cum += gs[g];
        }
        meta[0] = cut;
    }
}

__global__ void k_compact(const float* __restrict__ score, unsigned* __restrict__ meta,
                          int* __restrict__ cand, float* __restrict__ cscore) {
    int idx = blockIdx.x * 256 + threadIdx.x;
    unsigned bits = __float_as_uint(score[idx]);
    if (bits >= meta[0]) {
        unsigned pos = atomicAdd(&meta[1], 1u);
        if (pos < (unsigned)MAXCAND) {
            cand[pos] = idx;
            cscore[pos] = __uint_as_float(bits);
        }
    }
}

// ---------------- exact ranks, candidate-vs-candidate only ----------------
__global__ __launch_bounds__(256, 4)
void k_rank(const float* __restrict__ score, const float* __restrict__ validf,
            const float* __restrict__ box, const unsigned* __restrict__ meta,
            const int* __restrict__ cand, const float* __restrict__ cscore,
            float* __restrict__ score6, float* __restrict__ sc6,
            float* __restrict__ box6)
{
    __shared__ int pc[8][32];
    const int tid = threadIdx.x;
    const int il = tid & 31, js = tid >> 5;
    unsigned ncand = meta[1]; if (ncand > (unsigned)MAXCAND) ncand = MAXCAND;
    const int c = blockIdx.x * 32 + il;
    int i = -1; float si = 0.f;
    if (c < (int)ncand) { i = cand[c]; si = cscore[c]; }
    int cnt = 0;
    {
        const float4* cs4 = (const float4*)cscore;
        const int4*   cd4 = (const int4*)cand;
        const int q0 = js * 320;                // 8 splits x 320 float4 = 10240
        for (int q = 0; q < 320; ++q) {
            float4 v = cs4[q0 + q];
            int4   w = cd4[q0 + q];
            cnt += (v.x > si) || (v.x == si && w.x < i);
            cnt += (v.y > si) || (v.y == si && w.y < i);
            cnt += (v.z > si) || (v.z == si && w.z < i);
            cnt += (v.w > si) || (v.w == si && w.w < i);
        }
    }
    pc[js][il] = cnt;
    __syncthreads();
    if (js == 0 && i >= 0) {
        int rank = 0;
        #pragma unroll
        for (int q = 0; q < 8; ++q) rank += pc[q][il];
        if (rank < TOPK) {
            score6[rank] = si;
            sc6[rank] = (validf[i] != 0.f) ? si : -INFINITY;
            box6[rank * 4 + 0] = box[i * 4 + 0];
            box6[rank * 4 + 1] = box[i * 4 + 1];
            box6[rank * 4 + 2] = box[i * 4 + 2];
            box6[rank * 4 + 3] = box[i * 4 + 3];
        }
    }
}

// ---------------- pairwise IoU bitmask ----------------
__global__ void k_iou(const float* __restrict__ box6,
                      unsigned long long* __restrict__ mask)
{
    __shared__ float jb[64][4];
    const int blk = blockIdx.x;
    const int rb = blk / NWORDS, wb = blk - rb * NWORDS;
    const int tid = threadIdx.x;
    int j = wb * 64 + tid;
    if (j < TOPK) {
        jb[tid][0] = box6[j * 4 + 0]; jb[tid][1] = box6[j * 4 + 1];
        jb[tid][2] = box6[j * 4 + 2]; jb[tid][3] = box6[j * 4 + 3];
    } else {
        jb[tid][0] = 0.f; jb[tid][1] = 0.f; jb[tid][2] = 0.f; jb[tid][3] = 0.f;
    }
    __syncthreads();
    int i = rb * 64 + tid;
    if (i >= TOPK) return;
    float x1 = box6[i * 4], y1 = box6[i * 4 + 1], x2 = box6[i * 4 + 2], y2 = box6[i * 4 + 3];
    float ai = (x2 - x1) * (y2 - y1);
    unsigned long long bits = 0;
    for (int q = 0; q < 64; ++q) {
        float bx1 = jb[q][0], by1 = jb[q][1], bx2 = jb[q][2], by2 = jb[q][3];
        float xl = fmaxf(x1, bx1), yt = fmaxf(y1, by1);
        float xr = fminf(x2, bx2), yb = fminf(y2, by2);
        float inter = fmaxf(xr - xl, 0.f) * fmaxf(yb - yt, 0.f);
        float aj = (bx2 - bx1) * (by2 - by1);
        float iou = inter / (ai + aj - inter);
        if (iou > NMS_THRESH) bits |= (1ull << q);
    }
    mask[(size_t)i * NWORDS + wb] = bits;
}

// ---------------- sequential greedy NMS scan + output ----------------
__global__ void k_scan(const float* __restrict__ sc6, const float* __restrict__ score6,
                       const float* __restrict__ box6,
                       const unsigned long long* __restrict__ mask,
                       float* __restrict__ out)
{
    __shared__ unsigned long long remv[NWORDS];
    __shared__ int kept[POSTK];
    __shared__ int kcnt;
    __shared__ int kbs_s;
    __shared__ int klist[64];
    const int tid = threadIdx.x;
    for (int w = tid; w < NWORDS; w += 256) remv[w] = 0ull;
    if (tid == 0) kcnt = 0;
    __syncthreads();
    for (int b = 0; b < NWORDS; ++b) {
        if (tid < 64) {
            int i = b * 64 + tid;
            bool v = (i < TOPK) && (sc6[i] > -INFINITY);
            unsigned long long mi = 0ull;
            if (v) mi = mask[(size_t)i * NWORDS + b];
            unsigned long long validb = __ballot(v);
            unsigned long long cur = remv[b];
            int kc = kcnt;
            int kb = 0;
            unsigned long long cand2 = validb & ~cur;
            while (cand2 != 0ull && kc < POSTK) {
                int rr = __builtin_ctzll(cand2);
                unsigned long long mr = __shfl(mi, rr, 64);
                if (tid == 0) { kept[kc] = b * 64 + rr; klist[kb] = rr; }
                ++kb; ++kc;
                cur |= mr | (1ull << rr);
                cand2 = validb & ~cur;
            }
            if (tid == 0) { kcnt = kc; kbs_s = kb; remv[b] = cur; }
        }
        __syncthreads();
        int kb = kbs_s;
        if (kb > 0) {
            int w = b + 1 + tid;
            if (w < NWORDS) {
                unsigned long long acc = remv[w];
                for (int q = 0; q < kb; ++q) {
                    int rr = klist[q];
                    acc |= mask[(size_t)(b * 64 + rr) * NWORDS + w];
                }
                remv[w] = acc;
            }
        }
        __syncthreads();
        if (kcnt >= POSTK) break;
    }
    __syncthreads();
    int kc = kcnt;
    for (int n = tid; n < POSTK; n += 256) {
        float o0 = 0.f, o1 = 0.f, o2 = 0.f, o3 = 0.f, o4 = 0.f;
        if (n < kc) {
            int i = kept[n];
            o0 = box6[i * 4 + 0]; o1 = box6[i * 4 + 1];
            o2 = box6[i * 4 + 2]; o3 = box6[i * 4 + 3];
            o4 = score6[i];
        }
        out[n * 5 + 0] = o0; out[n * 5 + 1] = o1; out[n * 5 + 2] = o2;
        out[n * 5 + 3] = o3; out[n * 5 + 4] = o4;
    }
}

extern "C" void kernel_launch(void* const* d_in, const int* in_sizes, int n_in,
                              void* d_out, int out_size, void* d_ws, size_t ws_size,
                              hipStream_t stream)
{
    (void)in_sizes; (void)n_in; (void)out_size; (void)ws_size;
    const float* feat   = (const float*)d_in[1];   // (8,512,64,64) -> batch 0 only
    const float* conv_w = (const float*)d_in[2];
    const float* conv_b = (const float*)d_in[3];
    const float* cls_w  = (const float*)d_in[4];
    const float* cls_b  = (const float*)d_in[5];
    const float* reg_w  = (const float*)d_in[6];
    const float* reg_b  = (const float*)d_in[7];

    char* ws = (char*)d_ws;
    float*    t      = (float*)(ws + 0);          // 8,388,608 B (dead after k_heads)
    float*    heads  = (float*)(ws + 8388608);    //   737,280 B
    unsigned* hist   = (unsigned*)(ws + 9125888); //    16,384 B
    unsigned* hist2  = (unsigned*)(ws + 9142272); //    16,384 B
    unsigned* meta   = (unsigned*)(ws + 9158656); // [0]=cut [1]=ncand [2]=bin [3]=above
    int*      cand   = (int*)(ws + 9158720);      //    40,960 B
    float*    cscore = (float*)(ws + 9199680);    //    40,960 B
    float*    score  = (float*)(ws + 9240640);    //   147,456 B
    float*    validf = (float*)(ws + 9388096);    //   147,456 B
    float*    box    = (float*)(ws + 9535552);    //   589,824 B
    float*    score6 = (float*)(ws + 10125376);   //    24,576 B
    float*    sc6    = (float*)(ws + 10149952);   //    24,576 B
    float*    box6   = (float*)(ws + 10174528);   //    96,000 B (end 10,270,528)
    unsigned long long* mask = (unsigned long long*)(ws + 0);  // reuse t: 4,512,000 B

    k_zero   <<<33,   256, 0, stream>>>(hist);
    k_conv   <<<512,  256, 0, stream>>>(feat, conv_w, conv_b, t);
    k_heads  <<<2880, 64,  0, stream>>>(t, cls_w, cls_b, reg_w, reg_b, heads);
    k_decode <<<144,  256, 0, stream>>>(heads, score, validf, box, hist);
    k_cut1   <<<1,    256, 0, stream>>>(hist, meta);
    k_hist2  <<<144,  256, 0, stream>>>(score, meta, hist2);
    k_cut2   <<<1,    256, 0, stream>>>(hist2, meta);
    k_compact<<<144,  256, 0, stream>>>(score, meta, cand, cscore);
    k_rank   <<<320,  256, 0, stream>>>(score, validf, box, meta, cand, cscore, score6, sc6, box6);
    k_iou    <<<NWORDS * NWORDS, 64, 0, stream>>>(box6, mask);
    k_scan   <<<1,    256, 0, stream>>>(sc6, score6, box6, mask, (float*)d_out);
}

// Round 6
// 534.193 us; speedup vs baseline: 2.0427x; 2.0427x over previous
//
#include <hip/hip_runtime.h>
#include <math.h>

#define NMS_THRESH 0.7f
#define NANCH 36864
#define TOPK 6000
#define NWORDS 94    // ceil(6000/64)
#define POSTK 300
#define MAXCAND 10240

// ---------------- conv 3x3 + bias + relu, batch 0 only ----------------
// grid 512 = y_tile(16) x co_tile(32) (ct fastest -> concurrent blocks share
// feat rows in L2); block 256 (4 waves). block: 16 co x (4 rows x 64 cols).
// wave w owns co [cob+4w,+4) (uniform). thread: 4px x 4co.
// Feat: LDS [16ci][6rows][68] halo-free (validated r4/r5 edge logic).
// Weights: LDS [16ci][10tap][16co] -> thread's 4 co = ONE broadcast
// ds_read_b128 (all lanes same addr), no K$, no VGPR hoarding.
__global__ __launch_bounds__(256, 2)
void k_conv(const float* __restrict__ feat, const float* __restrict__ W,
            const float* __restrict__ bias, float* __restrict__ tout)
{
    __shared__ float sF[16 * 6 * 68];    // 6528 f = 26112 B
    __shared__ float sW[16 * 10 * 16];   // 2560 f = 10240 B

    const int blk = blockIdx.x;
    const int ct  = blk & 31;             // co-tile 0..31
    const int yt  = blk >> 5;             // y-tile 0..15
    const int cob = ct << 4;
    const int y0  = yt << 2;
    const int tid = threadIdx.x;
    const int lane = tid & 63;
    const int wid = __builtin_amdgcn_readfirstlane(tid >> 6);
    const int co0 = cob + (wid << 2);
    const int cwo = wid << 2;             // co offset inside sW tile
    const int ly = lane >> 4;             // row 0..3
    const int lx = (lane & 15) << 2;      // col 0..60 step 4

    // feat staging geometry: 16ci x 6rows x 17 float4-segs = 1632 units
    // (seg 16 = pad cols 64..67 zero-filled). 6/thread + 7th for tid<96.
    int g_ofs[7]; int l_ofs[7]; bool g_ok[7]; bool w_do[7];
    #pragma unroll
    for (int q = 0; q < 7; ++q) {
        int u = q * 256 + tid;            // valid < 1632
        int ci = u / 102; int rem = u - ci * 102;
        int rr = rem / 17; int seg = rem - rr * 17;
        int gy = y0 - 1 + rr;
        w_do[q] = (u < 1632);
        g_ok[q] = w_do[q] && (seg < 16) && (gy >= 0) && (gy < 64);
        g_ofs[q] = ((ci & 15) << 12) + ((gy & 63) << 6) + ((seg & 15) << 2);
        l_ofs[q] = ci * 408 + rr * 68 + (seg << 2);
    }

    // weight staging: thread -> (sci = tid>>4, sco = tid&15)
    const int sci = tid >> 4, sco = tid & 15;
    const float* wsrc = W + (size_t)(cob + sco) * 4608 + sci * 9;

    float acc[4][4];
    #pragma unroll
    for (int i = 0; i < 4; ++i)
        #pragma unroll
        for (int j = 0; j < 4; ++j) acc[i][j] = 0.f;

    for (int cc = 0; cc < 32; ++cc) {
        __syncthreads();                       // prev compute done
        // ---- stage feat chunk ----
        {
            const float* fsrc = feat + ((size_t)cc << 16);   // cc*16*4096
            float4 r[7];
            #pragma unroll
            for (int q = 0; q < 7; ++q)
                r[q] = g_ok[q] ? *(const float4*)(fsrc + g_ofs[q])
                               : make_float4(0.f, 0.f, 0.f, 0.f);
            #pragma unroll
            for (int q = 0; q < 7; ++q)
                if (w_do[q]) *(float4*)&sF[l_ofs[q]] = r[q];
        }
        // ---- stage weight chunk ----
        {
            const float* wp = wsrc + (size_t)cc * 144;       // 16 ci * 9
            float wv[9];
            #pragma unroll
            for (int t = 0; t < 9; ++t) wv[t] = wp[t];
            #pragma unroll
            for (int t = 0; t < 9; ++t)
                sW[sci * 160 + t * 16 + sco] = wv[t];
        }
        __syncthreads();
        // ---- compute 16 ci ----
        #pragma unroll 2
        for (int ci = 0; ci < 16; ++ci) {
            #pragma unroll
            for (int ky = 0; ky < 3; ++ky) {
                const float* rb = sF + ci * 408 + (ly + ky) * 68;
                float4 f4 = *(const float4*)&rb[lx];
                int c0 = lx ? lx - 1 : 0;
                int c5 = (lx < 60) ? lx + 4 : 63;
                float t0 = rb[c0];
                float t5 = rb[c5];
                float fr[6];
                fr[0] = lx ? t0 : 0.f;
                fr[1] = f4.x; fr[2] = f4.y; fr[3] = f4.z; fr[4] = f4.w;
                fr[5] = (lx < 60) ? t5 : 0.f;
                const float* wb = sW + ci * 160 + (ky * 3) * 16 + cwo;
                float w_[3][4];
                *(float4*)w_[0] = *(const float4*)(wb);        // kx=0, broadcast
                *(float4*)w_[1] = *(const float4*)(wb + 16);   // kx=1
                *(float4*)w_[2] = *(const float4*)(wb + 32);   // kx=2
                #pragma unroll
                for (int kx = 0; kx < 3; ++kx)
                    #pragma unroll
                    for (int i = 0; i < 4; ++i)
                        #pragma unroll
                        for (int j = 0; j < 4; ++j)
                            acc[i][j] = fmaf(fr[i + kx], w_[kx][j], acc[i][j]);
            }
        }
    }

    const int y = y0 + ly;
    #pragma unroll
    for (int j = 0; j < 4; ++j) {
        const float bv = bias[co0 + j];
        float4 o;
        o.x = fmaxf(acc[0][j] + bv, 0.f);
        o.y = fmaxf(acc[1][j] + bv, 0.f);
        o.z = fmaxf(acc[2][j] + bv, 0.f);
        o.w = fmaxf(acc[3][j] + bv, 0.f);
        *(float4*)&tout[((size_t)(co0 + j) << 12) + (y << 6) + lx] = o;
    }
}

// ---------------- 1x1 heads: wave = 64 px of one channel ----------------
__global__ __launch_bounds__(64)
void k_heads(const float* __restrict__ t, const float* __restrict__ cls_w,
             const float* __restrict__ cls_b, const float* __restrict__ reg_w,
             const float* __restrict__ reg_b, float* __restrict__ heads)
{
    const int bid = blockIdx.x;
    const int ch = bid % 45;                  // uniform
    const int pt = bid / 45;
    const int px = (pt << 6) + threadIdx.x;
    const float* wp; float bv;
    if (ch < 9) { wp = cls_w + ch * 512;       bv = cls_b[ch]; }
    else        { wp = reg_w + (ch - 9) * 512; bv = reg_b[ch - 9]; }
    float acc = bv;
    #pragma unroll 8
    for (int ci = 0; ci < 512; ++ci)
        acc = fmaf(t[((size_t)ci << 12) + px], wp[ci], acc);
    heads[((size_t)ch << 12) + px] = acc;
}

// ---------------- decode + sigmoid + clip + validity + hist1 (fused) ----------------
__global__ void k_decode(const float* __restrict__ heads,
                         float* __restrict__ score, float* __restrict__ validf,
                         float* __restrict__ box, unsigned* __restrict__ hist)
{
    __shared__ unsigned lh[4096];
    const int tid = threadIdx.x;
    for (int q = tid; q < 4096; q += 256) lh[q] = 0u;
    __syncthreads();

    int idx = blockIdx.x * 256 + tid;
    int p = idx / 9, a = idx - p * 9;
    int yq = p >> 6, xq = p & 63;
    const double scl[3] = {128.0, 256.0, 512.0};
    const double rat[3] = {0.5, 1.0, 2.0};
    double s = scl[a / 3], r = rat[a % 3];
    float bw = (float)(s * sqrt(1.0 / r) * 0.5);
    float bh = (float)(s * sqrt(r) * 0.5);
    float sx = xq * 16.0f + 8.0f;
    float sy = yq * 16.0f + 8.0f;
    float a0 = sx - bw, a1 = sy - bh, a2 = sx + bw, a3 = sy + bh;
    float wa = a2 - a0, ha = a3 - a1;
    float cx = a0 + 0.5f * wa, cy = a1 + 0.5f * ha;
    float logit = heads[(size_t)a * 4096 + p];
    float dx = heads[(size_t)(9  + 4 * a) * 4096 + p];
    float dy = heads[(size_t)(10 + 4 * a) * 4096 + p];
    float dw = fminf(heads[(size_t)(11 + 4 * a) * 4096 + p], 4.135166556742356f);
    float dh = fminf(heads[(size_t)(12 + 4 * a) * 4096 + p], 4.135166556742356f);
    float pcx = dx * wa + cx, pcy = dy * ha + cy;
    float pw = expf(dw) * wa, ph = expf(dh) * ha;
    float x1 = pcx - 0.5f * pw, y1 = pcy - 0.5f * ph;
    float x2 = pcx + 0.5f * pw, y2 = pcy + 0.5f * ph;
    x1 = fminf(fmaxf(x1, 0.f), 1024.f); y1 = fminf(fmaxf(y1, 0.f), 1024.f);
    x2 = fminf(fmaxf(x2, 0.f), 1024.f); y2 = fminf(fmaxf(y2, 0.f), 1024.f);
    float wv = x2 - x1, hv = y2 - y1;
    float sc = 1.f / (1.f + expf(-logit));
    score[idx]  = sc;
    validf[idx] = (wv >= 1.f && hv >= 1.f) ? 1.f : 0.f;
    box[idx * 4 + 0] = x1; box[idx * 4 + 1] = y1;
    box[idx * 4 + 2] = x2; box[idx * 4 + 3] = y2;

    atomicAdd(&lh[__float_as_uint(sc) >> 19], 1u);
    __syncthreads();
    for (int q = tid; q < 4096; q += 256) if (lh[q]) atomicAdd(&hist[q], lh[q]);
}

// ---------------- top-k cutoff machinery ----------------
__global__ void k_zero(unsigned* __restrict__ p) {
    int i = blockIdx.x * 256 + threadIdx.x;
    if (i < 8448) p[i] = 0u;   // hist(4096) + hist2(4096) + meta
}

__global__ void k_cut1(const unsigned* __restrict__ hist, unsigned* __restrict__ meta) {
    __shared__ unsigned hh[4096];
    __shared__ unsigned gs[256];
    int tid = threadIdx.x;
    for (int q = tid; q < 4096; q += 256) hh[q] = hist[q];
    __syncthreads();
    unsigned s = 0;
    #pragma unroll
    for (int k = 0; k < 16; ++k) s += hh[tid * 16 + k];
    gs[tid] = s;
    __syncthreads();
    if (tid == 0) {
        unsigned cum = 0;
        for (int g = 255; g >= 0; --g) {
            if (cum + gs[g] >= (unsigned)TOPK) {
                for (int b = g * 16 + 15; b >= g * 16; --b) {
                    if (cum + hh[b] >= (unsigned)TOPK) { meta[2] = (unsigned)b; meta[3] = cum; break; }
                    cum += hh[b];
                }
                break;
            }
            cum += gs[g];
        }
    }
}

__global__ void k_hist2(const float* __restrict__ score, const unsigned* __restrict__ meta,
                        unsigned* __restrict__ hist2) {
    int idx = blockIdx.x * 256 + threadIdx.x;
    unsigned bits = __float_as_uint(score[idx]);
    if ((bits >> 19) == meta[2]) atomicAdd(&hist2[(bits >> 7) & 0xFFFu], 1u);
}

__global__ void k_cut2(const unsigned* __restrict__ hist2, unsigned* __restrict__ meta) {
    __shared__ unsigned hh[4096];
    __shared__ unsigned gs[256];
    int tid = threadIdx.x;
    for (int q = tid; q < 4096; q += 256) hh[q] = hist2[q];
    __syncthreads();
    unsigned s = 0;
    #pragma unroll
    for (int k = 0; k < 16; ++k) s += hh[tid * 16 + k];
    gs[tid] = s;
    __syncthreads();
    if (tid == 0) {
        unsigned cum = meta[3];
        unsigned B = meta[2];
        unsigned cut = B << 19;
        for (int g = 255; g >= 0; --g) {
            if (cum + gs[g] >= (unsigned)TOPK) {
                for (int b = g * 16 + 15; b >= g * 16; --b) {
                    cum += hh[b];
                    if (cum >= (unsigned)TOPK) { cut = (B << 19) | ((unsigned)b << 7); break; }
                }
                break;
            }
            cum += gs[g];
        }
        meta[0] = cut;
    }
}

__global__ void k_compact(const float* __restrict__ score, unsigned* __restrict__ meta,
                          int* __restrict__ cand, float* __restrict__ cscore) {
    int idx = blockIdx.x * 256 + threadIdx.x;
    unsigned bits = __float_as_uint(score[idx]);
    if (bits >= meta[0]) {
        unsigned pos = atomicAdd(&meta[1], 1u);
        if (pos < (unsigned)MAXCAND) {
            cand[pos] = idx;
            cscore[pos] = __uint_as_float(bits);
        }
    }
}

// ---------------- exact ranks, candidate-vs-candidate only ----------------
__global__ __launch_bounds__(256, 4)
void k_rank(const float* __restrict__ score, const float* __restrict__ validf,
            const float* __restrict__ box, const unsigned* __restrict__ meta,
            const int* __restrict__ cand, const float* __restrict__ cscore,
            float* __restrict__ score6, float* __restrict__ sc6,
            float* __restrict__ box6)
{
    __shared__ int pc[8][32];
    const int tid = threadIdx.x;
    const int il = tid & 31, js = tid >> 5;
    unsigned ncand = meta[1]; if (ncand > (unsigned)MAXCAND) ncand = MAXCAND;
    const int c = blockIdx.x * 32 + il;
    int i = -1; float si = 0.f;
    if (c < (int)ncand) { i = cand[c]; si = cscore[c]; }
    int cnt = 0;
    {
        const float4* cs4 = (const float4*)cscore;
        const int4*   cd4 = (const int4*)cand;
        const int q0 = js * 320;                // 8 splits x 320 float4 = 10240
        for (int q = 0; q < 320; ++q) {
            float4 v = cs4[q0 + q];
            int4   w = cd4[q0 + q];
            cnt += (v.x > si) || (v.x == si && w.x < i);
            cnt += (v.y > si) || (v.y == si && w.y < i);
            cnt += (v.z > si) || (v.z == si && w.z < i);
            cnt += (v.w > si) || (v.w == si && w.w < i);
        }
    }
    pc[js][il] = cnt;
    __syncthreads();
    if (js == 0 && i >= 0) {
        int rank = 0;
        #pragma unroll
        for (int q = 0; q < 8; ++q) rank += pc[q][il];
        if (rank < TOPK) {
            score6[rank] = si;
            sc6[rank] = (validf[i] != 0.f) ? si : -INFINITY;
            box6[rank * 4 + 0] = box[i * 4 + 0];
            box6[rank * 4 + 1] = box[i * 4 + 1];
            box6[rank * 4 + 2] = box[i * 4 + 2];
            box6[rank * 4 + 3] = box[i * 4 + 3];
        }
    }
}

// ---------------- pairwise IoU bitmask ----------------
__global__ void k_iou(const float* __restrict__ box6,
                      unsigned long long* __restrict__ mask)
{
    __shared__ float jb[64][4];
    const int blk = blockIdx.x;
    const int rb = blk / NWORDS, wb = blk - rb * NWORDS;
    const int tid = threadIdx.x;
    int j = wb * 64 + tid;
    if (j < TOPK) {
        jb[tid][0] = box6[j * 4 + 0]; jb[tid][1] = box6[j * 4 + 1];
        jb[tid][2] = box6[j * 4 + 2]; jb[tid][3] = box6[j * 4 + 3];
    } else {
        jb[tid][0] = 0.f; jb[tid][1] = 0.f; jb[tid][2] = 0.f; jb[tid][3] = 0.f;
    }
    __syncthreads();
    int i = rb * 64 + tid;
    if (i >= TOPK) return;
    float x1 = box6[i * 4], y1 = box6[i * 4 + 1], x2 = box6[i * 4 + 2], y2 = box6[i * 4 + 3];
    float ai = (x2 - x1) * (y2 - y1);
    unsigned long long bits = 0;
    for (int q = 0; q < 64; ++q) {
        float bx1 = jb[q][0], by1 = jb[q][1], bx2 = jb[q][2], by2 = jb[q][3];
        float xl = fmaxf(x1, bx1), yt = fmaxf(y1, by1);
        float xr = fminf(x2, bx2), yb = fminf(y2, by2);
        float inter = fmaxf(xr - xl, 0.f) * fmaxf(yb - yt, 0.f);
        float aj = (bx2 - bx1) * (by2 - by1);
        float iou = inter / (ai + aj - inter);
        if (iou > NMS_THRESH) bits |= (1ull << q);
    }
    mask[(size_t)i * NWORDS + wb] = bits;
}

// ---------------- sequential greedy NMS scan + output ----------------
__global__ void k_scan(const float* __restrict__ sc6, const float* __restrict__ score6,
                       const float* __restrict__ box6,
                       const unsigned long long* __restrict__ mask,
                       float* __restrict__ out)
{
    __shared__ unsigned long long remv[NWORDS];
    __shared__ int kept[POSTK];
    __shared__ int kcnt;
    __shared__ int kbs_s;
    __shared__ int klist[64];
    const int tid = threadIdx.x;
    for (int w = tid; w < NWORDS; w += 256) remv[w] = 0ull;
    if (tid == 0) kcnt = 0;
    __syncthreads();
    for (int b = 0; b < NWORDS; ++b) {
        if (tid < 64) {
            int i = b * 64 + tid;
            bool v = (i < TOPK) && (sc6[i] > -INFINITY);
            unsigned long long mi = 0ull;
            if (v) mi = mask[(size_t)i * NWORDS + b];
            unsigned long long validb = __ballot(v);
            unsigned long long cur = remv[b];
            int kc = kcnt;
            int kb = 0;
            unsigned long long cand2 = validb & ~cur;
            while (cand2 != 0ull && kc < POSTK) {
                int rr = __builtin_ctzll(cand2);
                unsigned long long mr = __shfl(mi, rr, 64);
                if (tid == 0) { kept[kc] = b * 64 + rr; klist[kb] = rr; }
                ++kb; ++kc;
                cur |= mr | (1ull << rr);
                cand2 = validb & ~cur;
            }
            if (tid == 0) { kcnt = kc; kbs_s = kb; remv[b] = cur; }
        }
        __syncthreads();
        int kb = kbs_s;
        if (kb > 0) {
            int w = b + 1 + tid;
            if (w < NWORDS) {
                unsigned long long acc = remv[w];
                for (int q = 0; q < kb; ++q) {
                    int rr = klist[q];
                    acc |= mask[(size_t)(b * 64 + rr) * NWORDS + w];
                }
                remv[w] = acc;
            }
        }
        __syncthreads();
        if (kcnt >= POSTK) break;
    }
    __syncthreads();
    int kc = kcnt;
    for (int n = tid; n < POSTK; n += 256) {
        float o0 = 0.f, o1 = 0.f, o2 = 0.f, o3 = 0.f, o4 = 0.f;
        if (n < kc) {
            int i = kept[n];
            o0 = box6[i * 4 + 0]; o1 = box6[i * 4 + 1];
            o2 = box6[i * 4 + 2]; o3 = box6[i * 4 + 3];
            o4 = score6[i];
        }
        out[n * 5 + 0] = o0; out[n * 5 + 1] = o1; out[n * 5 + 2] = o2;
        out[n * 5 + 3] = o3; out[n * 5 + 4] = o4;
    }
}

extern "C" void kernel_launch(void* const* d_in, const int* in_sizes, int n_in,
                              void* d_out, int out_size, void* d_ws, size_t ws_size,
                              hipStream_t stream)
{
    (void)in_sizes; (void)n_in; (void)out_size; (void)ws_size;
    const float* feat   = (const float*)d_in[1];   // (8,512,64,64) -> batch 0 only
    const float* conv_w = (const float*)d_in[2];
    const float* conv_b = (const float*)d_in[3];
    const float* cls_w  = (const float*)d_in[4];
    const float* cls_b  = (const float*)d_in[5];
    const float* reg_w  = (const float*)d_in[6];
    const float* reg_b  = (const float*)d_in[7];

    char* ws = (char*)d_ws;
    float*    t      = (float*)(ws + 0);          // 8,388,608 B (dead after k_heads)
    float*    heads  = (float*)(ws + 8388608);    //   737,280 B
    unsigned* hist   = (unsigned*)(ws + 9125888); //    16,384 B
    unsigned* hist2  = (unsigned*)(ws + 9142272); //    16,384 B
    unsigned* meta   = (unsigned*)(ws + 9158656); // [0]=cut [1]=ncand [2]=bin [3]=above
    int*      cand   = (int*)(ws + 9158720);      //    40,960 B
    float*    cscore = (float*)(ws + 9199680);    //    40,960 B
    float*    score  = (float*)(ws + 9240640);    //   147,456 B
    float*    validf = (float*)(ws + 9388096);    //   147,456 B
    float*    box    = (float*)(ws + 9535552);    //   589,824 B
    float*    score6 = (float*)(ws + 10125376);   //    24,576 B
    float*    sc6    = (float*)(ws + 10149952);   //    24,576 B
    float*    box6   = (float*)(ws + 10174528);   //    96,000 B (end 10,270,528)
    unsigned long long* mask = (unsigned long long*)(ws + 0);  // reuse t: 4,512,000 B

    k_zero   <<<33,   256, 0, stream>>>(hist);
    k_conv   <<<512,  256, 0, stream>>>(feat, conv_w, conv_b, t);
    k_heads  <<<2880, 64,  0, stream>>>(t, cls_w, cls_b, reg_w, reg_b, heads);
    k_decode <<<144,  256, 0, stream>>>(heads, score, validf, box, hist);
    k_cut1   <<<1,    256, 0, stream>>>(hist, meta);
    k_hist2  <<<144,  256, 0, stream>>>(score, meta, hist2);
    k_cut2   <<<1,    256, 0, stream>>>(hist2, meta);
    k_compact<<<144,  256, 0, stream>>>(score, meta, cand, cscore);
    k_rank   <<<320,  256, 0, stream>>>(score, validf, box, meta, cand, cscore, score6, sc6, box6);
    k_iou    <<<NWORDS * NWORDS, 64, 0, stream>>>(box6, mask);
    k_scan   <<<1,    256, 0, stream>>>(sc6, score6, box6, mask, (float*)d_out);
}

// Round 7
// 520.677 us; speedup vs baseline: 2.0957x; 1.0260x over previous
//
#include <hip/hip_runtime.h>
#include <math.h>

#define NMS_THRESH 0.7f
#define NANCH 36864
#define TOPK 6000
#define NWORDS 94    // ceil(6000/64)
#define POSTK 300
#define MAXCAND 10240

// ---------------- conv 3x3 + bias + relu, batch 0 only ----------------
// grid 512 = y_tile(16) x co_tile(32); block 256 (4 waves).
// block: 16 co x (4 rows x 64 cols); wave w owns co [cob+4w,+4); thread 4px x 4co.
// Feat: LDS [2][16ci][6rows][68] double-buffered halo-free (r6-validated geometry).
// Weights: LDS [16ci][10tap][16co] single-buffered; global loads for cc+1 are
// issued BEFORE the compute phase (regs r[7], wregN[9]) and stored after ->
// global latency hides under the 16-ci FMA burst. 62,464 B LDS <= 64 KB.
__global__ __launch_bounds__(256, 2)
void k_conv(const float* __restrict__ feat, const float* __restrict__ W,
            const float* __restrict__ bias, float* __restrict__ tout)
{
    __shared__ float sF[2 * 6528];    // 52,224 B
    __shared__ float sW[16 * 10 * 16]; // 10,240 B

    const int blk = blockIdx.x;
    const int ct  = blk & 31;
    const int yt  = blk >> 5;
    const int cob = ct << 4;
    const int y0  = yt << 2;
    const int tid = threadIdx.x;
    const int lane = tid & 63;
    const int wid = __builtin_amdgcn_readfirstlane(tid >> 6);
    const int co0 = cob + (wid << 2);
    const int cwo = wid << 2;
    const int ly = lane >> 4;
    const int lx = (lane & 15) << 2;

    // feat staging geometry (r6-validated): 1632 float4 units
    int g_ofs[7]; int l_ofs[7]; bool g_ok[7]; bool w_do[7];
    #pragma unroll
    for (int q = 0; q < 7; ++q) {
        int u = q * 256 + tid;
        int ci = u / 102; int rem = u - ci * 102;
        int rr = rem / 17; int seg = rem - rr * 17;
        int gy = y0 - 1 + rr;
        w_do[q] = (u < 1632);
        g_ok[q] = w_do[q] && (seg < 16) && (gy >= 0) && (gy < 64);
        g_ofs[q] = ((ci & 15) << 12) + ((gy & 63) << 6) + ((seg & 15) << 2);
        l_ofs[q] = ci * 408 + rr * 68 + (seg << 2);
    }

    // weight staging: thread (sci=tid>>4, sco=tid&15) loads 9 taps
    const int sci = tid >> 4, sco = tid & 15;
    const float* wsrc = W + (size_t)(cob + sco) * 4608 + sci * 9;

    float acc[4][4];
    #pragma unroll
    for (int i = 0; i < 4; ++i)
        #pragma unroll
        for (int j = 0; j < 4; ++j) acc[i][j] = 0.f;

    // prologue: stage feat(0) into buf 0, load wreg(0)
    float wreg[9];
    {
        float4 r0[7];
        #pragma unroll
        for (int q = 0; q < 7; ++q)
            r0[q] = g_ok[q] ? *(const float4*)(feat + g_ofs[q])
                            : make_float4(0.f, 0.f, 0.f, 0.f);
        #pragma unroll
        for (int q = 0; q < 7; ++q)
            if (w_do[q]) *(float4*)&sF[l_ofs[q]] = r0[q];
        #pragma unroll
        for (int t = 0; t < 9; ++t) wreg[t] = wsrc[t];
    }

    int p = 0;
    for (int cc = 0; cc < 32; ++cc) {
        const bool more = cc < 31;
        // A: write weights(cc) to sW from wreg
        #pragma unroll
        for (int t = 0; t < 9; ++t)
            sW[sci * 160 + t * 16 + sco] = wreg[t];
        // B: issue global loads for cc+1
        float4 r[7]; float wregN[9];
        if (more) {
            const float* fsrc = feat + ((size_t)(cc + 1) << 16);
            #pragma unroll
            for (int q = 0; q < 7; ++q)
                r[q] = g_ok[q] ? *(const float4*)(fsrc + g_ofs[q])
                               : make_float4(0.f, 0.f, 0.f, 0.f);
            const float* wp = wsrc + (size_t)(cc + 1) * 144;
            #pragma unroll
            for (int t = 0; t < 9; ++t) wregN[t] = wp[t];
        }
        __syncthreads();   // sW(cc) + sF[p] stores visible
        // C: compute 16 ci from sF[p], sW
        const int pbase = p * 6528;
        #pragma unroll 2
        for (int ci = 0; ci < 16; ++ci) {
            #pragma unroll
            for (int ky = 0; ky < 3; ++ky) {
                const float* rb = sF + pbase + ci * 408 + (ly + ky) * 68;
                float4 f4 = *(const float4*)&rb[lx];
                int c0 = lx ? lx - 1 : 0;
                int c5 = (lx < 60) ? lx + 4 : 63;
                float t0 = rb[c0];
                float t5 = rb[c5];
                float fr[6];
                fr[0] = lx ? t0 : 0.f;
                fr[1] = f4.x; fr[2] = f4.y; fr[3] = f4.z; fr[4] = f4.w;
                fr[5] = (lx < 60) ? t5 : 0.f;
                const float* wb = sW + ci * 160 + (ky * 3) * 16 + cwo;
                float w_[3][4];
                *(float4*)w_[0] = *(const float4*)(wb);        // broadcast b128
                *(float4*)w_[1] = *(const float4*)(wb + 16);
                *(float4*)w_[2] = *(const float4*)(wb + 32);
                #pragma unroll
                for (int kx = 0; kx < 3; ++kx)
                    #pragma unroll
                    for (int i = 0; i < 4; ++i)
                        #pragma unroll
                        for (int j = 0; j < 4; ++j)
                            acc[i][j] = fmaf(fr[i + kx], w_[kx][j], acc[i][j]);
            }
        }
        // D: store staged feat(cc+1) to sF[p^1]; roll weights
        if (more) {
            const int wb2 = (p ^ 1) * 6528;
            #pragma unroll
            for (int q = 0; q < 7; ++q)
                if (w_do[q]) *(float4*)&sF[wb2 + l_ofs[q]] = r[q];
            #pragma unroll
            for (int t = 0; t < 9; ++t) wreg[t] = wregN[t];
        }
        __syncthreads();   // compute done (sW reusable), sF[p^1] stores ordered
        p ^= 1;
    }

    const int y = y0 + ly;
    #pragma unroll
    for (int j = 0; j < 4; ++j) {
        const float bv = bias[co0 + j];
        float4 o;
        o.x = fmaxf(acc[0][j] + bv, 0.f);
        o.y = fmaxf(acc[1][j] + bv, 0.f);
        o.z = fmaxf(acc[2][j] + bv, 0.f);
        o.w = fmaxf(acc[3][j] + bv, 0.f);
        *(float4*)&tout[((size_t)(co0 + j) << 12) + (y << 6) + lx] = o;
    }
}

// ---------------- 1x1 heads: wave = 64 px of one channel ----------------
__global__ __launch_bounds__(64)
void k_heads(const float* __restrict__ t, const float* __restrict__ cls_w,
             const float* __restrict__ cls_b, const float* __restrict__ reg_w,
             const float* __restrict__ reg_b, float* __restrict__ heads)
{
    const int bid = blockIdx.x;
    const int ch = bid % 45;                  // uniform
    const int pt = bid / 45;
    const int px = (pt << 6) + threadIdx.x;
    const float* wp; float bv;
    if (ch < 9) { wp = cls_w + ch * 512;       bv = cls_b[ch]; }
    else        { wp = reg_w + (ch - 9) * 512; bv = reg_b[ch - 9]; }
    float acc = bv;
    #pragma unroll 8
    for (int ci = 0; ci < 512; ++ci)
        acc = fmaf(t[((size_t)ci << 12) + px], wp[ci], acc);
    heads[((size_t)ch << 12) + px] = acc;
}

// ---------------- decode + sigmoid + clip + validity + hist1 (fused) ----------------
__global__ void k_decode(const float* __restrict__ heads,
                         float* __restrict__ score, float* __restrict__ validf,
                         float* __restrict__ box, unsigned* __restrict__ hist)
{
    __shared__ unsigned lh[4096];
    const int tid = threadIdx.x;
    for (int q = tid; q < 4096; q += 256) lh[q] = 0u;
    __syncthreads();

    int idx = blockIdx.x * 256 + tid;
    int p = idx / 9, a = idx - p * 9;
    int yq = p >> 6, xq = p & 63;
    const double scl[3] = {128.0, 256.0, 512.0};
    const double rat[3] = {0.5, 1.0, 2.0};
    double s = scl[a / 3], r = rat[a % 3];
    float bw = (float)(s * sqrt(1.0 / r) * 0.5);
    float bh = (float)(s * sqrt(r) * 0.5);
    float sx = xq * 16.0f + 8.0f;
    float sy = yq * 16.0f + 8.0f;
    float a0 = sx - bw, a1 = sy - bh, a2 = sx + bw, a3 = sy + bh;
    float wa = a2 - a0, ha = a3 - a1;
    float cx = a0 + 0.5f * wa, cy = a1 + 0.5f * ha;
    float logit = heads[(size_t)a * 4096 + p];
    float dx = heads[(size_t)(9  + 4 * a) * 4096 + p];
    float dy = heads[(size_t)(10 + 4 * a) * 4096 + p];
    float dw = fminf(heads[(size_t)(11 + 4 * a) * 4096 + p], 4.135166556742356f);
    float dh = fminf(heads[(size_t)(12 + 4 * a) * 4096 + p], 4.135166556742356f);
    float pcx = dx * wa + cx, pcy = dy * ha + cy;
    float pw = expf(dw) * wa, ph = expf(dh) * ha;
    float x1 = pcx - 0.5f * pw, y1 = pcy - 0.5f * ph;
    float x2 = pcx + 0.5f * pw, y2 = pcy + 0.5f * ph;
    x1 = fminf(fmaxf(x1, 0.f), 1024.f); y1 = fminf(fmaxf(y1, 0.f), 1024.f);
    x2 = fminf(fmaxf(x2, 0.f), 1024.f); y2 = fminf(fmaxf(y2, 0.f), 1024.f);
    float wv = x2 - x1, hv = y2 - y1;
    float sc = 1.f / (1.f + expf(-logit));
    score[idx]  = sc;
    validf[idx] = (wv >= 1.f && hv >= 1.f) ? 1.f : 0.f;
    box[idx * 4 + 0] = x1; box[idx * 4 + 1] = y1;
    box[idx * 4 + 2] = x2; box[idx * 4 + 3] = y2;

    atomicAdd(&lh[__float_as_uint(sc) >> 19], 1u);
    __syncthreads();
    for (int q = tid; q < 4096; q += 256) if (lh[q]) atomicAdd(&hist[q], lh[q]);
}

// ---------------- top-k cutoff machinery ----------------
__global__ void k_zero(unsigned* __restrict__ p) {
    int i = blockIdx.x * 256 + threadIdx.x;
    if (i < 8448) p[i] = 0u;   // hist(4096) + hist2(4096) + meta
}

__global__ void k_cut1(const unsigned* __restrict__ hist, unsigned* __restrict__ meta) {
    __shared__ unsigned hh[4096];
    __shared__ unsigned gs[256];
    int tid = threadIdx.x;
    for (int q = tid; q < 4096; q += 256) hh[q] = hist[q];
    __syncthreads();
    unsigned s = 0;
    #pragma unroll
    for (int k = 0; k < 16; ++k) s += hh[tid * 16 + k];
    gs[tid] = s;
    __syncthreads();
    if (tid == 0) {
        unsigned cum = 0;
        for (int g = 255; g >= 0; --g) {
            if (cum + gs[g] >= (unsigned)TOPK) {
                for (int b = g * 16 + 15; b >= g * 16; --b) {
                    if (cum + hh[b] >= (unsigned)TOPK) { meta[2] = (unsigned)b; meta[3] = cum; break; }
                    cum += hh[b];
                }
                break;
            }
            cum += gs[g];
        }
    }
}

__global__ void k_hist2(const float* __restrict__ score, const unsigned* __restrict__ meta,
                        unsigned* __restrict__ hist2) {
    int idx = blockIdx.x * 256 + threadIdx.x;
    unsigned bits = __float_as_uint(score[idx]);
    if ((bits >> 19) == meta[2]) atomicAdd(&hist2[(bits >> 7) & 0xFFFu], 1u);
}

__global__ void k_cut2(const unsigned* __restrict__ hist2, unsigned* __restrict__ meta) {
    __shared__ unsigned hh[4096];
    __shared__ unsigned gs[256];
    int tid = threadIdx.x;
    for (int q = tid; q < 4096; q += 256) hh[q] = hist2[q];
    __syncthreads();
    unsigned s = 0;
    #pragma unroll
    for (int k = 0; k < 16; ++k) s += hh[tid * 16 + k];
    gs[tid] = s;
    __syncthreads();
    if (tid == 0) {
        unsigned cum = meta[3];
        unsigned B = meta[2];
        unsigned cut = B << 19;
        for (int g = 255; g >= 0; --g) {
            if (cum + gs[g] >= (unsigned)TOPK) {
                for (int b = g * 16 + 15; b >= g * 16; --b) {
                    cum += hh[b];
                    if (cum >= (unsigned)TOPK) { cut = (B << 19) | ((unsigned)b << 7); break; }
                }
                break;
            }
            cum += gs[g];
        }
        meta[0] = cut;
    }
}

__global__ void k_compact(const float* __restrict__ score, unsigned* __restrict__ meta,
                          int* __restrict__ cand, float* __restrict__ cscore) {
    int idx = blockIdx.x * 256 + threadIdx.x;
    unsigned bits = __float_as_uint(score[idx]);
    if (bits >= meta[0]) {
        unsigned pos = atomicAdd(&meta[1], 1u);
        if (pos < (unsigned)MAXCAND) {
            cand[pos] = idx;
            cscore[pos] = __uint_as_float(bits);
        }
    }
}

// ---------------- exact ranks, candidate-vs-candidate only ----------------
__global__ __launch_bounds__(256, 4)
void k_rank(const float* __restrict__ score, const float* __restrict__ validf,
            const float* __restrict__ box, const unsigned* __restrict__ meta,
            const int* __restrict__ cand, const float* __restrict__ cscore,
            float* __restrict__ score6, float* __restrict__ sc6,
            float* __restrict__ box6)
{
    __shared__ int pc[8][32];
    const int tid = threadIdx.x;
    const int il = tid & 31, js = tid >> 5;
    unsigned ncand = meta[1]; if (ncand > (unsigned)MAXCAND) ncand = MAXCAND;
    const int c = blockIdx.x * 32 + il;
    int i = -1; float si = 0.f;
    if (c < (int)ncand) { i = cand[c]; si = cscore[c]; }
    int cnt = 0;
    {
        const float4* cs4 = (const float4*)cscore;
        const int4*   cd4 = (const int4*)cand;
        const int q0 = js * 320;                // 8 splits x 320 float4 = 10240
        for (int q = 0; q < 320; ++q) {
            float4 v = cs4[q0 + q];
            int4   w = cd4[q0 + q];
            cnt += (v.x > si) || (v.x == si && w.x < i);
            cnt += (v.y > si) || (v.y == si && w.y < i);
            cnt += (v.z > si) || (v.z == si && w.z < i);
            cnt += (v.w > si) || (v.w == si && w.w < i);
        }
    }
    pc[js][il] = cnt;
    __syncthreads();
    if (js == 0 && i >= 0) {
        int rank = 0;
        #pragma unroll
        for (int q = 0; q < 8; ++q) rank += pc[q][il];
        if (rank < TOPK) {
            score6[rank] = si;
            sc6[rank] = (validf[i] != 0.f) ? si : -INFINITY;
            box6[rank * 4 + 0] = box[i * 4 + 0];
            box6[rank * 4 + 1] = box[i * 4 + 1];
            box6[rank * 4 + 2] = box[i * 4 + 2];
            box6[rank * 4 + 3] = box[i * 4 + 3];
        }
    }
}

// ---------------- fused NMS: kept boxes in LDS, IoU on the fly ----------------
// 1 block x 512 threads (8 waves). Per 64-candidate block: 8-way split scan
// vs previously-kept boxes (LDS), ballot-OR; wave 0 resolves intra-block
// keeps serially with shfl-broadcast IoU. No global mask traffic.
__global__ __launch_bounds__(512)
void k_nms(const float* __restrict__ sc6, const float* __restrict__ score6,
           const float* __restrict__ box6, float* __restrict__ out)
{
    __shared__ float kx1[POSTK], ky1[POSTK], kx2[POSTK], ky2[POSTK], kar[POSTK];
    __shared__ int kidx[POSTK];
    __shared__ unsigned long long pOR[8];
    __shared__ int kcnt_s;
    const int tid = threadIdx.x, lane = tid & 63, wv = tid >> 6;

    if (tid == 0) kcnt_s = 0;
    // preload block 0 candidate
    int i0 = lane;            // < 6000
    float cx1 = box6[i0 * 4 + 0], cy1 = box6[i0 * 4 + 1];
    float cx2 = box6[i0 * 4 + 2], cy2 = box6[i0 * 4 + 3];
    float csc = sc6[i0];
    __syncthreads();

    for (int b = 0; b < NWORDS; ++b) {
        // prefetch next block
        float nx1 = 0.f, ny1 = 0.f, nx2 = 0.f, ny2 = 0.f, nsc = -INFINITY;
        if (b + 1 < NWORDS) {
            int ni = (b + 1) * 64 + lane; if (ni >= TOPK) ni = TOPK - 1;
            nx1 = box6[ni * 4 + 0]; ny1 = box6[ni * 4 + 1];
            nx2 = box6[ni * 4 + 2]; ny2 = box6[ni * 4 + 3];
            nsc = sc6[ni];
        }
        const int i = b * 64 + lane;
        const bool v = (i < TOPK) && (csc > -INFINITY);
        const float ar = (cx2 - cx1) * (cy2 - cy1);
        const int kc = kcnt_s;               // uniform snapshot
        bool dead = false;
        for (int j = wv; j < kc; j += 8) {
            float xl = fmaxf(kx1[j], cx1), yt = fmaxf(ky1[j], cy1);
            float xr = fminf(kx2[j], cx2), yb = fminf(ky2[j], cy2);
            float inter = fmaxf(xr - xl, 0.f) * fmaxf(yb - yt, 0.f);
            float iou = inter / (kar[j] + ar - inter);
            dead = dead || (iou > NMS_THRESH);
        }
        pOR[wv] = __ballot(dead);
        __syncthreads();
        if (wv == 0) {
            unsigned long long supp = pOR[0] | pOR[1] | pOR[2] | pOR[3]
                                    | pOR[4] | pOR[5] | pOR[6] | pOR[7];
            unsigned long long validb = __ballot(v);
            unsigned long long cand2 = validb & ~supp;
            int kc2 = kc;
            while (cand2 != 0ull && kc2 < POSTK) {
                int rr = __builtin_ctzll(cand2);
                float rx1 = __shfl(cx1, rr, 64), ry1 = __shfl(cy1, rr, 64);
                float rx2 = __shfl(cx2, rr, 64), ry2 = __shfl(cy2, rr, 64);
                float rar = __shfl(ar, rr, 64);
                if (lane == 0) {
                    kx1[kc2] = rx1; ky1[kc2] = ry1;
                    kx2[kc2] = rx2; ky2[kc2] = ry2;
                    kar[kc2] = rar; kidx[kc2] = b * 64 + rr;
                }
                float xl = fmaxf(rx1, cx1), yt = fmaxf(ry1, cy1);
                float xr = fminf(rx2, cx2), yb = fminf(ry2, cy2);
                float inter = fmaxf(xr - xl, 0.f) * fmaxf(yb - yt, 0.f);
                float iou = inter / (rar + ar - inter);
                unsigned long long sm = __ballot(iou > NMS_THRESH) | (1ull << rr);
                cand2 &= ~sm;
                ++kc2;
            }
            if (lane == 0) kcnt_s = kc2;
        }
        __syncthreads();
        if (kcnt_s >= POSTK) break;
        cx1 = nx1; cy1 = ny1; cx2 = nx2; cy2 = ny2; csc = nsc;
    }

    const int kc = kcnt_s;
    for (int n = tid; n < POSTK; n += 512) {
        float o0 = 0.f, o1 = 0.f, o2 = 0.f, o3 = 0.f, o4 = 0.f;
        if (n < kc) {
            int i = kidx[n];
            o0 = box6[i * 4 + 0]; o1 = box6[i * 4 + 1];
            o2 = box6[i * 4 + 2]; o3 = box6[i * 4 + 3];
            o4 = score6[i];
        }
        out[n * 5 + 0] = o0; out[n * 5 + 1] = o1; out[n * 5 + 2] = o2;
        out[n * 5 + 3] = o3; out[n * 5 + 4] = o4;
    }
}

extern "C" void kernel_launch(void* const* d_in, const int* in_sizes, int n_in,
                              void* d_out, int out_size, void* d_ws, size_t ws_size,
                              hipStream_t stream)
{
    (void)in_sizes; (void)n_in; (void)out_size; (void)ws_size;
    const float* feat   = (const float*)d_in[1];   // (8,512,64,64) -> batch 0 only
    const float* conv_w = (const float*)d_in[2];
    const float* conv_b = (const float*)d_in[3];
    const float* cls_w  = (const float*)d_in[4];
    const float* cls_b  = (const float*)d_in[5];
    const float* reg_w  = (const float*)d_in[6];
    const float* reg_b  = (const float*)d_in[7];

    char* ws = (char*)d_ws;
    float*    t      = (float*)(ws + 0);          // 8,388,608 B (dead after k_heads)
    float*    heads  = (float*)(ws + 8388608);    //   737,280 B
    unsigned* hist   = (unsigned*)(ws + 9125888); //    16,384 B
    unsigned* hist2  = (unsigned*)(ws + 9142272); //    16,384 B
    unsigned* meta   = (unsigned*)(ws + 9158656); // [0]=cut [1]=ncand [2]=bin [3]=above
    int*      cand   = (int*)(ws + 9158720);      //    40,960 B
    float*    cscore = (float*)(ws + 9199680);    //    40,960 B
    float*    score  = (float*)(ws + 9240640);    //   147,456 B
    float*    validf = (float*)(ws + 9388096);    //   147,456 B
    float*    box    = (float*)(ws + 9535552);    //   589,824 B
    float*    score6 = (float*)(ws + 10125376);   //    24,576 B
    float*    sc6    = (float*)(ws + 10149952);   //    24,576 B
    float*    box6   = (float*)(ws + 10174528);   //    96,000 B (end 10,270,528)

    k_zero   <<<33,   256, 0, stream>>>(hist);
    k_conv   <<<512,  256, 0, stream>>>(feat, conv_w, conv_b, t);
    k_heads  <<<2880, 64,  0, stream>>>(t, cls_w, cls_b, reg_w, reg_b, heads);
    k_decode <<<144,  256, 0, stream>>>(heads, score, validf, box, hist);
    k_cut1   <<<1,    256, 0, stream>>>(hist, meta);
    k_hist2  <<<144,  256, 0, stream>>>(score, meta, hist2);
    k_cut2   <<<1,    256, 0, stream>>>(hist2, meta);
    k_compact<<<144,  256, 0, stream>>>(score, meta, cand, cscore);
    k_rank   <<<320,  256, 0, stream>>>(score, validf, box, meta, cand, cscore, score6, sc6, box6);
    k_nms    <<<1,    512, 0, stream>>>(sc6, score6, box6, (float*)d_out);
}

// Round 8
// 511.310 us; speedup vs baseline: 2.1341x; 1.0183x over previous
//
#include <hip/hip_runtime.h>
#include <math.h>

#define NMS_THRESH 0.7f
#define NANCH 36864
#define TOPK 6000
#define NWORDS 94    // ceil(6000/64)
#define POSTK 300
#define MAXCAND 10240

// ---------------- conv 3x3 + bias + relu, batch 0 only ----------------
// grid 512 = y_tile(16) x co_tile(32); block 128 (2 waves).
// block: 16 co x (4 rows x 64 cols); wave w owns co [cob+8w,+8); thread 4px x 8co.
// Feat: LDS [2][16ci][6rows][68] double-buffered (r7-validated geometry).
// Weights: LDS [16ci][172] (taps*16+co, pad to 172 for write-bank spread);
// staged via paired b64 writes; read as broadcast b128 pairs.
// Ratio: per (ci,ky) per wave ~40 LDS-read cyc vs 192 FMA SIMD-cyc -> VALU-bound.
__global__ __launch_bounds__(128, 1)
void k_conv(const float* __restrict__ feat, const float* __restrict__ W,
            const float* __restrict__ bias, float* __restrict__ tout)
{
    __shared__ float sF[2 * 6528];    // 52,224 B
    __shared__ float sW[16 * 172];    // 11,008 B  (63,232 total <= 64 KB)

    const int blk = blockIdx.x;
    const int ct  = blk & 31;
    const int yt  = blk >> 5;
    const int cob = ct << 4;
    const int y0  = yt << 2;
    const int tid = threadIdx.x;
    const int lane = tid & 63;
    const int wid = __builtin_amdgcn_readfirstlane(tid >> 6);  // 0..1
    const int cwo = wid << 3;
    const int co0 = cob + cwo;
    const int ly = lane >> 4;
    const int lx = (lane & 15) << 2;

    // feat staging geometry (r7-validated): 1632 float4 units, 13/thread
    int g_ofs[13]; int l_ofs[13]; bool g_ok[13]; bool w_do[13];
    #pragma unroll
    for (int q = 0; q < 13; ++q) {
        int u = q * 128 + tid;
        int ci = u / 102; int rem = u - ci * 102;
        int rr = rem / 17; int seg = rem - rr * 17;
        int gy = y0 - 1 + rr;
        w_do[q] = (u < 1632);
        g_ok[q] = w_do[q] && (seg < 16) && (gy >= 0) && (gy < 64);
        g_ofs[q] = ((ci & 15) << 12) + ((gy & 63) << 6) + ((seg & 15) << 2);
        l_ofs[q] = (ci & 15) * 408 + rr * 68 + (seg << 2);
    }

    // weight staging: thread (sci=tid>>3, sc2=tid&7) loads co pair {2sc2,2sc2+1}
    const int sci = tid >> 3, sc2 = tid & 7;
    const float* wsrc0 = W + (size_t)(cob + 2 * sc2) * 4608 + sci * 9;
    const float* wsrc1 = wsrc0 + 4608;

    float acc[4][8];
    #pragma unroll
    for (int i = 0; i < 4; ++i)
        #pragma unroll
        for (int j = 0; j < 8; ++j) acc[i][j] = 0.f;

    // prologue: stage feat(0) into buf 0, load wreg(0)
    float wreg[18];
    {
        float4 r0[13];
        #pragma unroll
        for (int q = 0; q < 13; ++q)
            r0[q] = g_ok[q] ? *(const float4*)(feat + g_ofs[q])
                            : make_float4(0.f, 0.f, 0.f, 0.f);
        #pragma unroll
        for (int q = 0; q < 13; ++q)
            if (w_do[q]) *(float4*)&sF[l_ofs[q]] = r0[q];
        #pragma unroll
        for (int t = 0; t < 9; ++t) { wreg[t] = wsrc0[t]; wreg[9 + t] = wsrc1[t]; }
    }

    int p = 0;
    for (int cc = 0; cc < 32; ++cc) {
        const bool more = cc < 31;
        // A: write weights(cc) to sW as paired b64 (co 2sc2, 2sc2+1)
        #pragma unroll
        for (int t = 0; t < 9; ++t) {
            float2 wp2; wp2.x = wreg[t]; wp2.y = wreg[9 + t];
            *(float2*)&sW[sci * 172 + t * 16 + 2 * sc2] = wp2;
        }
        // B: issue global loads for cc+1
        float4 r[13]; float wregN[18];
        if (more) {
            const float* fsrc = feat + ((size_t)(cc + 1) << 16);
            #pragma unroll
            for (int q = 0; q < 13; ++q)
                r[q] = g_ok[q] ? *(const float4*)(fsrc + g_ofs[q])
                               : make_float4(0.f, 0.f, 0.f, 0.f);
            const float* wp0 = wsrc0 + (size_t)(cc + 1) * 144;
            const float* wp1 = wsrc1 + (size_t)(cc + 1) * 144;
            #pragma unroll
            for (int t = 0; t < 9; ++t) { wregN[t] = wp0[t]; wregN[9 + t] = wp1[t]; }
        }
        __syncthreads();   // sW(cc) + sF[p] stores visible
        // C: compute 16 ci from sF[p], sW
        const int pbase = p * 6528;
        #pragma unroll 2
        for (int ci = 0; ci < 16; ++ci) {
            #pragma unroll
            for (int ky = 0; ky < 3; ++ky) {
                const float* rb = sF + pbase + ci * 408 + (ly + ky) * 68;
                float4 f4 = *(const float4*)&rb[lx];
                int c0 = lx ? lx - 1 : 0;
                int c5 = (lx < 60) ? lx + 4 : 63;
                float t0 = rb[c0];
                float t5 = rb[c5];
                float fr[6];
                fr[0] = lx ? t0 : 0.f;
                fr[1] = f4.x; fr[2] = f4.y; fr[3] = f4.z; fr[4] = f4.w;
                fr[5] = (lx < 60) ? t5 : 0.f;
                const float* wb = sW + ci * 172 + ky * 48 + cwo;
                float w_[3][8];
                *(float4*)&w_[0][0] = *(const float4*)(wb);        // broadcasts
                *(float4*)&w_[0][4] = *(const float4*)(wb + 4);
                *(float4*)&w_[1][0] = *(const float4*)(wb + 16);
                *(float4*)&w_[1][4] = *(const float4*)(wb + 20);
                *(float4*)&w_[2][0] = *(const float4*)(wb + 32);
                *(float4*)&w_[2][4] = *(const float4*)(wb + 36);
                #pragma unroll
                for (int kx = 0; kx < 3; ++kx)
                    #pragma unroll
                    for (int i = 0; i < 4; ++i)
                        #pragma unroll
                        for (int j = 0; j < 8; ++j)
                            acc[i][j] = fmaf(fr[i + kx], w_[kx][j], acc[i][j]);
            }
        }
        // D: store staged feat(cc+1) to sF[p^1]; roll weights
        if (more) {
            const int wb2 = (p ^ 1) * 6528;
            #pragma unroll
            for (int q = 0; q < 13; ++q)
                if (w_do[q]) *(float4*)&sF[wb2 + l_ofs[q]] = r[q];
            #pragma unroll
            for (int t = 0; t < 18; ++t) wreg[t] = wregN[t];
        }
        __syncthreads();
        p ^= 1;
    }

    const int y = y0 + ly;
    #pragma unroll
    for (int j = 0; j < 8; ++j) {
        const float bv = bias[co0 + j];
        float4 o;
        o.x = fmaxf(acc[0][j] + bv, 0.f);
        o.y = fmaxf(acc[1][j] + bv, 0.f);
        o.z = fmaxf(acc[2][j] + bv, 0.f);
        o.w = fmaxf(acc[3][j] + bv, 0.f);
        *(float4*)&tout[((size_t)(co0 + j) << 12) + (y << 6) + lx] = o;
    }
}

// ---------------- 1x1 heads: wave = 64 px of one channel ----------------
__global__ __launch_bounds__(64)
void k_heads(const float* __restrict__ t, const float* __restrict__ cls_w,
             const float* __restrict__ cls_b, const float* __restrict__ reg_w,
             const float* __restrict__ reg_b, float* __restrict__ heads)
{
    const int bid = blockIdx.x;
    const int ch = bid % 45;                  // uniform
    const int pt = bid / 45;
    const int px = (pt << 6) + threadIdx.x;
    const float* wp; float bv;
    if (ch < 9) { wp = cls_w + ch * 512;       bv = cls_b[ch]; }
    else        { wp = reg_w + (ch - 9) * 512; bv = reg_b[ch - 9]; }
    float acc = bv;
    #pragma unroll 8
    for (int ci = 0; ci < 512; ++ci)
        acc = fmaf(t[((size_t)ci << 12) + px], wp[ci], acc);
    heads[((size_t)ch << 12) + px] = acc;
}

// ---------------- decode + sigmoid + clip + validity + hist1 (fused) ----------------
__global__ void k_decode(const float* __restrict__ heads,
                         float* __restrict__ score, float* __restrict__ validf,
                         float* __restrict__ box, unsigned* __restrict__ hist)
{
    __shared__ unsigned lh[4096];
    const int tid = threadIdx.x;
    for (int q = tid; q < 4096; q += 256) lh[q] = 0u;
    __syncthreads();

    int idx = blockIdx.x * 256 + tid;
    int p = idx / 9, a = idx - p * 9;
    int yq = p >> 6, xq = p & 63;
    const double scl[3] = {128.0, 256.0, 512.0};
    const double rat[3] = {0.5, 1.0, 2.0};
    double s = scl[a / 3], r = rat[a % 3];
    float bw = (float)(s * sqrt(1.0 / r) * 0.5);
    float bh = (float)(s * sqrt(r) * 0.5);
    float sx = xq * 16.0f + 8.0f;
    float sy = yq * 16.0f + 8.0f;
    float a0 = sx - bw, a1 = sy - bh, a2 = sx + bw, a3 = sy + bh;
    float wa = a2 - a0, ha = a3 - a1;
    float cx = a0 + 0.5f * wa, cy = a1 + 0.5f * ha;
    float logit = heads[(size_t)a * 4096 + p];
    float dx = heads[(size_t)(9  + 4 * a) * 4096 + p];
    float dy = heads[(size_t)(10 + 4 * a) * 4096 + p];
    float dw = fminf(heads[(size_t)(11 + 4 * a) * 4096 + p], 4.135166556742356f);
    float dh = fminf(heads[(size_t)(12 + 4 * a) * 4096 + p], 4.135166556742356f);
    float pcx = dx * wa + cx, pcy = dy * ha + cy;
    float pw = expf(dw) * wa, ph = expf(dh) * ha;
    float x1 = pcx - 0.5f * pw, y1 = pcy - 0.5f * ph;
    float x2 = pcx + 0.5f * pw, y2 = pcy + 0.5f * ph;
    x1 = fminf(fmaxf(x1, 0.f), 1024.f); y1 = fminf(fmaxf(y1, 0.f), 1024.f);
    x2 = fminf(fmaxf(x2, 0.f), 1024.f); y2 = fminf(fmaxf(y2, 0.f), 1024.f);
    float wv = x2 - x1, hv = y2 - y1;
    float sc = 1.f / (1.f + expf(-logit));
    score[idx]  = sc;
    validf[idx] = (wv >= 1.f && hv >= 1.f) ? 1.f : 0.f;
    box[idx * 4 + 0] = x1; box[idx * 4 + 1] = y1;
    box[idx * 4 + 2] = x2; box[idx * 4 + 3] = y2;

    atomicAdd(&lh[__float_as_uint(sc) >> 19], 1u);
    __syncthreads();
    for (int q = tid; q < 4096; q += 256) if (lh[q]) atomicAdd(&hist[q], lh[q]);
}

// ---------------- top-k cutoff machinery ----------------
__global__ void k_zero(unsigned* __restrict__ p) {
    int i = blockIdx.x * 256 + threadIdx.x;
    if (i < 8448) p[i] = 0u;   // hist(4096) + hist2(4096) + meta
}

__global__ void k_cut1(const unsigned* __restrict__ hist, unsigned* __restrict__ meta) {
    __shared__ unsigned hh[4096];
    __shared__ unsigned gs[256];
    int tid = threadIdx.x;
    for (int q = tid; q < 4096; q += 256) hh[q] = hist[q];
    __syncthreads();
    unsigned s = 0;
    #pragma unroll
    for (int k = 0; k < 16; ++k) s += hh[tid * 16 + k];
    gs[tid] = s;
    __syncthreads();
    if (tid == 0) {
        unsigned cum = 0;
        for (int g = 255; g >= 0; --g) {
            if (cum + gs[g] >= (unsigned)TOPK) {
                for (int b = g * 16 + 15; b >= g * 16; --b) {
                    if (cum + hh[b] >= (unsigned)TOPK) { meta[2] = (unsigned)b; meta[3] = cum; break; }
                    cum += hh[b];
                }
                break;
            }
            cum += gs[g];
        }
    }
}

__global__ void k_hist2(const float* __restrict__ score, const unsigned* __restrict__ meta,
                        unsigned* __restrict__ hist2) {
    int idx = blockIdx.x * 256 + threadIdx.x;
    unsigned bits = __float_as_uint(score[idx]);
    if ((bits >> 19) == meta[2]) atomicAdd(&hist2[(bits >> 7) & 0xFFFu], 1u);
}

__global__ void k_cut2(const unsigned* __restrict__ hist2, unsigned* __restrict__ meta) {
    __shared__ unsigned hh[4096];
    __shared__ unsigned gs[256];
    int tid = threadIdx.x;
    for (int q = tid; q < 4096; q += 256) hh[q] = hist2[q];
    __syncthreads();
    unsigned s = 0;
    #pragma unroll
    for (int k = 0; k < 16; ++k) s += hh[tid * 16 + k];
    gs[tid] = s;
    __syncthreads();
    if (tid == 0) {
        unsigned cum = meta[3];
        unsigned B = meta[2];
        unsigned cut = B << 19;
        for (int g = 255; g >= 0; --g) {
            if (cum + gs[g] >= (unsigned)TOPK) {
                for (int b = g * 16 + 15; b >= g * 16; --b) {
                    cum += hh[b];
                    if (cum >= (unsigned)TOPK) { cut = (B << 19) | ((unsigned)b << 7); break; }
                }
                break;
            }
            cum += gs[g];
        }
        meta[0] = cut;
    }
}

__global__ void k_compact(const float* __restrict__ score, unsigned* __restrict__ meta,
                          int* __restrict__ cand, float* __restrict__ cscore) {
    int idx = blockIdx.x * 256 + threadIdx.x;
    unsigned bits = __float_as_uint(score[idx]);
    if (bits >= meta[0]) {
        unsigned pos = atomicAdd(&meta[1], 1u);
        if (pos < (unsigned)MAXCAND) {
            cand[pos] = idx;
            cscore[pos] = __uint_as_float(bits);
        }
    }
}

// ---------------- exact ranks, candidate-vs-candidate only ----------------
__global__ __launch_bounds__(256, 4)
void k_rank(const float* __restrict__ score, const float* __restrict__ validf,
            const float* __restrict__ box, const unsigned* __restrict__ meta,
            const int* __restrict__ cand, const float* __restrict__ cscore,
            float* __restrict__ score6, float* __restrict__ sc6,
            float* __restrict__ box6)
{
    __shared__ int pc[8][32];
    const int tid = threadIdx.x;
    const int il = tid & 31, js = tid >> 5;
    unsigned ncand = meta[1]; if (ncand > (unsigned)MAXCAND) ncand = MAXCAND;
    const int c = blockIdx.x * 32 + il;
    int i = -1; float si = 0.f;
    if (c < (int)ncand) { i = cand[c]; si = cscore[c]; }
    int cnt = 0;
    {
        const float4* cs4 = (const float4*)cscore;
        const int4*   cd4 = (const int4*)cand;
        const int q0 = js * 320;                // 8 splits x 320 float4 = 10240
        for (int q = 0; q < 320; ++q) {
            float4 v = cs4[q0 + q];
            int4   w = cd4[q0 + q];
            cnt += (v.x > si) || (v.x == si && w.x < i);
            cnt += (v.y > si) || (v.y == si && w.y < i);
            cnt += (v.z > si) || (v.z == si && w.z < i);
            cnt += (v.w > si) || (v.w == si && w.w < i);
        }
    }
    pc[js][il] = cnt;
    __syncthreads();
    if (js == 0 && i >= 0) {
        int rank = 0;
        #pragma unroll
        for (int q = 0; q < 8; ++q) rank += pc[q][il];
        if (rank < TOPK) {
            score6[rank] = si;
            sc6[rank] = (validf[i] != 0.f) ? si : -INFINITY;
            box6[rank * 4 + 0] = box[i * 4 + 0];
            box6[rank * 4 + 1] = box[i * 4 + 1];
            box6[rank * 4 + 2] = box[i * 4 + 2];
            box6[rank * 4 + 3] = box[i * 4 + 3];
        }
    }
}

// ---------------- fused NMS: kept boxes in LDS, IoU on the fly ----------------
__global__ __launch_bounds__(512)
void k_nms(const float* __restrict__ sc6, const float* __restrict__ score6,
           const float* __restrict__ box6, float* __restrict__ out)
{
    __shared__ float kx1[POSTK], ky1[POSTK], kx2[POSTK], ky2[POSTK], kar[POSTK];
    __shared__ int kidx[POSTK];
    __shared__ unsigned long long pOR[8];
    __shared__ int kcnt_s;
    const int tid = threadIdx.x, lane = tid & 63, wv = tid >> 6;

    if (tid == 0) kcnt_s = 0;
    int i0 = lane;
    float cx1 = box6[i0 * 4 + 0], cy1 = box6[i0 * 4 + 1];
    float cx2 = box6[i0 * 4 + 2], cy2 = box6[i0 * 4 + 3];
    float csc = sc6[i0];
    __syncthreads();

    for (int b = 0; b < NWORDS; ++b) {
        float nx1 = 0.f, ny1 = 0.f, nx2 = 0.f, ny2 = 0.f, nsc = -INFINITY;
        if (b + 1 < NWORDS) {
            int ni = (b + 1) * 64 + lane; if (ni >= TOPK) ni = TOPK - 1;
            nx1 = box6[ni * 4 + 0]; ny1 = box6[ni * 4 + 1];
            nx2 = box6[ni * 4 + 2]; ny2 = box6[ni * 4 + 3];
            nsc = sc6[ni];
        }
        const int i = b * 64 + lane;
        const bool v = (i < TOPK) && (csc > -INFINITY);
        const float ar = (cx2 - cx1) * (cy2 - cy1);
        const int kc = kcnt_s;
        bool dead = false;
        for (int j = wv; j < kc; j += 8) {
            float xl = fmaxf(kx1[j], cx1), yt = fmaxf(ky1[j], cy1);
            float xr = fminf(kx2[j], cx2), yb = fminf(ky2[j], cy2);
            float inter = fmaxf(xr - xl, 0.f) * fmaxf(yb - yt, 0.f);
            float iou = inter / (kar[j] + ar - inter);
            dead = dead || (iou > NMS_THRESH);
        }
        pOR[wv] = __ballot(dead);
        __syncthreads();
        if (wv == 0) {
            unsigned long long supp = pOR[0] | pOR[1] | pOR[2] | pOR[3]
                                    | pOR[4] | pOR[5] | pOR[6] | pOR[7];
            unsigned long long validb = __ballot(v);
            unsigned long long cand2 = validb & ~supp;
            int kc2 = kc;
            while (cand2 != 0ull && kc2 < POSTK) {
                int rr = __builtin_ctzll(cand2);
                float rx1 = __shfl(cx1, rr, 64), ry1 = __shfl(cy1, rr, 64);
                float rx2 = __shfl(cx2, rr, 64), ry2 = __shfl(cy2, rr, 64);
                float rar = __shfl(ar, rr, 64);
                if (lane == 0) {
                    kx1[kc2] = rx1; ky1[kc2] = ry1;
                    kx2[kc2] = rx2; ky2[kc2] = ry2;
                    kar[kc2] = rar; kidx[kc2] = b * 64 + rr;
                }
                float xl = fmaxf(rx1, cx1), yt = fmaxf(ry1, cy1);
                float xr = fminf(rx2, cx2), yb = fminf(ry2, cy2);
                float inter = fmaxf(xr - xl, 0.f) * fmaxf(yb - yt, 0.f);
                float iou = inter / (rar + ar - inter);
                unsigned long long sm = __ballot(iou > NMS_THRESH) | (1ull << rr);
                cand2 &= ~sm;
                ++kc2;
            }
            if (lane == 0) kcnt_s = kc2;
        }
        __syncthreads();
        if (kcnt_s >= POSTK) break;
        cx1 = nx1; cy1 = ny1; cx2 = nx2; cy2 = ny2; csc = nsc;
    }

    const int kc = kcnt_s;
    for (int n = tid; n < POSTK; n += 512) {
        float o0 = 0.f, o1 = 0.f, o2 = 0.f, o3 = 0.f, o4 = 0.f;
        if (n < kc) {
            int i = kidx[n];
            o0 = box6[i * 4 + 0]; o1 = box6[i * 4 + 1];
            o2 = box6[i * 4 + 2]; o3 = box6[i * 4 + 3];
            o4 = score6[i];
        }
        out[n * 5 + 0] = o0; out[n * 5 + 1] = o1; out[n * 5 + 2] = o2;
        out[n * 5 + 3] = o3; out[n * 5 + 4] = o4;
    }
}

extern "C" void kernel_launch(void* const* d_in, const int* in_sizes, int n_in,
                              void* d_out, int out_size, void* d_ws, size_t ws_size,
                              hipStream_t stream)
{
    (void)in_sizes; (void)n_in; (void)out_size; (void)ws_size;
    const float* feat   = (const float*)d_in[1];   // (8,512,64,64) -> batch 0 only
    const float* conv_w = (const float*)d_in[2];
    const float* conv_b = (const float*)d_in[3];
    const float* cls_w  = (const float*)d_in[4];
    const float* cls_b  = (const float*)d_in[5];
    const float* reg_w  = (const float*)d_in[6];
    const float* reg_b  = (const float*)d_in[7];

    char* ws = (char*)d_ws;
    float*    t      = (float*)(ws + 0);          // 8,388,608 B (dead after k_heads)
    float*    heads  = (float*)(ws + 8388608);    //   737,280 B
    unsigned* hist   = (unsigned*)(ws + 9125888); //    16,384 B
    unsigned* hist2  = (unsigned*)(ws + 9142272); //    16,384 B
    unsigned* meta   = (unsigned*)(ws + 9158656); // [0]=cut [1]=ncand [2]=bin [3]=above
    int*      cand   = (int*)(ws + 9158720);      //    40,960 B
    float*    cscore = (float*)(ws + 9199680);    //    40,960 B
    float*    score  = (float*)(ws + 9240640);    //   147,456 B
    float*    validf = (float*)(ws + 9388096);    //   147,456 B
    float*    box    = (float*)(ws + 9535552);    //   589,824 B
    float*    score6 = (float*)(ws + 10125376);   //    24,576 B
    float*    sc6    = (float*)(ws + 10149952);   //    24,576 B
    float*    box6   = (float*)(ws + 10174528);   //    96,000 B (end 10,270,528)

    k_zero   <<<33,   256, 0, stream>>>(hist);
    k_conv   <<<512,  128, 0, stream>>>(feat, conv_w, conv_b, t);
    k_heads  <<<2880, 64,  0, stream>>>(t, cls_w, cls_b, reg_w, reg_b, heads);
    k_decode <<<144,  256, 0, stream>>>(heads, score, validf, box, hist);
    k_cut1   <<<1,    256, 0, stream>>>(hist, meta);
    k_hist2  <<<144,  256, 0, stream>>>(score, meta, hist2);
    k_cut2   <<<1,    256, 0, stream>>>(hist2, meta);
    k_compact<<<144,  256, 0, stream>>>(score, meta, cand, cscore);
    k_rank   <<<320,  256, 0, stream>>>(score, validf, box, meta, cand, cscore, score6, sc6, box6);
    k_nms    <<<1,    512, 0, stream>>>(sc6, score6, box6, (float*)d_out);
}